// Round 2
// baseline (7178.441 us; speedup 1.0000x reference)
//
#include <hip/hip_runtime.h>
#include <hip/hip_bf16.h>

#define BB 64
#define NQ 512
#define NN 1000
#define DD 256

typedef __attribute__((ext_vector_type(8))) __bf16 bf16x8;
typedef __attribute__((ext_vector_type(4))) float floatx4;

__device__ __forceinline__ float b2f(unsigned short u) {
  return __uint_as_float(((unsigned)u) << 16);
}
__device__ __forceinline__ unsigned short f2b(float f) {
  __hip_bfloat16 h = __float2bfloat16(f);  // RNE
  return *reinterpret_cast<unsigned short*>(&h);
}
__device__ __forceinline__ void unpack8(uint4 u, float* f) {
  f[0] = __uint_as_float(u.x << 16); f[1] = __uint_as_float(u.x & 0xffff0000u);
  f[2] = __uint_as_float(u.y << 16); f[3] = __uint_as_float(u.y & 0xffff0000u);
  f[4] = __uint_as_float(u.z << 16); f[5] = __uint_as_float(u.z & 0xffff0000u);
  f[6] = __uint_as_float(u.w << 16); f[7] = __uint_as_float(u.w & 0xffff0000u);
}
// fp32 -> bf16x8 fragment (RNE), 8 contiguous floats
__device__ __forceinline__ bf16x8 cvt8(const float* p) {
  float4 f0 = *(const float4*)(p);
  float4 f1 = *(const float4*)(p + 4);
  bf16x8 a;
  a[0] = (__bf16)f0.x; a[1] = (__bf16)f0.y; a[2] = (__bf16)f0.z; a[3] = (__bf16)f0.w;
  a[4] = (__bf16)f1.x; a[5] = (__bf16)f1.y; a[6] = (__bf16)f1.z; a[7] = (__bf16)f1.w;
  return a;
}

// ---------------- weight transposes fp32 -> bf16 (Wc split hi/lo) ----------------
__global__ void transpose_w(const float* Wk, const float* Wv, const float* Wq,
                            const float* Wc, unsigned short* WkT, unsigned short* WvT,
                            unsigned short* WqT, unsigned short* WcThi,
                            unsigned short* WcTlo) {
  int c = blockIdx.x;   // output row (original column)
  int k = threadIdx.x;  // 0..255
  if (blockIdx.y == 3) {
    float w = Wc[k * 256 + c];
    unsigned short h = f2b(w);
    WcThi[c * 256 + k] = h;
    WcTlo[c * 256 + k] = f2b(w - b2f(h));
    return;
  }
  const float* W; unsigned short* WT;
  switch (blockIdx.y) {
    case 0:  W = Wk; WT = WkT; break;
    case 1:  W = Wv; WT = WvT; break;
    default: W = Wq; WT = WqT; break;  // first 256 rows of [257][256]
  }
  WT[c * 256 + k] = f2b(W[k * 256 + c]);
}

// ---------------- all-inf row flags ----------------
__global__ void mask_flags(const float* mask, int* flags) {
  int i = blockIdx.x, b = blockIdx.y, lane = threadIdx.x;
  const float* mp = mask + ((size_t)b * NQ + i) * NN;
  bool allinf = true;
  for (int m = lane; m < NN; m += 64) allinf = allinf && isinf(mp[m]);
  unsigned long long bal = __ballot(allinf);
  if (lane == 0) flags[b * NQ + i] = (bal == ~0ull) ? 1 : 0;
}

// ---------------- k,v projections (MFMA bf16, fp32 A converted inline) ----------------
__global__ __launch_bounds__(256) void kv_proj(const float* nodes,
    const unsigned short* WkT, const unsigned short* WvT,
    unsigned short* kb, unsigned short* vb) {
  int b = blockIdx.z;
  int wave = threadIdx.x >> 6, lane = threadIdx.x & 63;
  int quad = lane >> 4, r16 = lane & 15;
  int mbase = blockIdx.x * 64 + wave * 16;
  int arow = mbase + r16;
  // rows >= NN read row 0 (in-bounds garbage); their C rows aren't stored
  const float* ap = nodes + ((size_t)b * NN + (arow < NN ? arow : 0)) * DD;
  int colbase = blockIdx.y * 64;
  floatx4 ak[4], av[4];
  #pragma unroll
  for (int s = 0; s < 4; ++s) {
    #pragma unroll
    for (int r = 0; r < 4; ++r) { ak[s][r] = 0.f; av[s][r] = 0.f; }
  }
  for (int kk = 0; kk < DD; kk += 32) {
    int k0 = kk + quad * 8;
    bf16x8 a = cvt8(ap + k0);
    #pragma unroll
    for (int s = 0; s < 4; ++s) {
      int col = colbase + s * 16 + r16;
      bf16x8 bk = *(const bf16x8*)(WkT + col * DD + k0);
      bf16x8 bv = *(const bf16x8*)(WvT + col * DD + k0);
      ak[s] = __builtin_amdgcn_mfma_f32_16x16x32_bf16(a, bk, ak[s], 0, 0, 0);
      av[s] = __builtin_amdgcn_mfma_f32_16x16x32_bf16(a, bv, av[s], 0, 0, 0);
    }
  }
  #pragma unroll
  for (int s = 0; s < 4; ++s) {
    #pragma unroll
    for (int r = 0; r < 4; ++r) {
      int row = mbase + quad * 4 + r;
      if (row < NN) {
        int col = colbase + s * 16 + r16;
        size_t o = ((size_t)b * NN + row) * DD + col;
        kb[o] = f2b(ak[s][r]);
        vb[o] = f2b(av[s][r]);
      }
    }
  }
}

// ---------------- q projection (MFMA bf16 + attr rank-1 term, bf16 out) ----------------
__global__ __launch_bounds__(256) void q_proj(const float* eln,
    const float* attr, const unsigned short* WqT, const float* Wq,
    unsigned short* qf) {
  int b = blockIdx.z;
  int wave = threadIdx.x >> 6, lane = threadIdx.x & 63;
  int quad = lane >> 4, r16 = lane & 15;
  int mbase = blockIdx.x * 64 + wave * 16;
  const float* ap = eln + ((size_t)b * NQ + mbase + r16) * DD;
  int colbase = blockIdx.y * 64;
  floatx4 acc[4];
  #pragma unroll
  for (int s = 0; s < 4; ++s) {
    #pragma unroll
    for (int r = 0; r < 4; ++r) acc[s][r] = 0.f;
  }
  for (int kk = 0; kk < DD; kk += 32) {
    int k0 = kk + quad * 8;
    bf16x8 a = cvt8(ap + k0);
    #pragma unroll
    for (int s = 0; s < 4; ++s) {
      int col = colbase + s * 16 + r16;
      bf16x8 bq = *(const bf16x8*)(WqT + col * DD + k0);
      acc[s] = __builtin_amdgcn_mfma_f32_16x16x32_bf16(a, bq, acc[s], 0, 0, 0);
    }
  }
  #pragma unroll
  for (int s = 0; s < 4; ++s) {
    #pragma unroll
    for (int r = 0; r < 4; ++r) {
      int row = mbase + quad * 4 + r;
      int col = colbase + s * 16 + r16;
      float aval = attr[b * NQ + row];
      float wq = Wq[256 * 256 + col];  // row 256 of Wq_last (fp32)
      qf[((size_t)b * NQ + row) * DD + col] = f2b(acc[s][r] + aval * wq);
    }
  }
}

// ---------------- fused MHA, fp32 online softmax ----------------
// thread = (query row in 16-row tile, head); bf16 K/V chunks staged in LDS,
// segment-padded (16 shorts used + 8 pad) -> 2-way bank alias only (free).
#define CH 32
#define SEGS 24
__global__ __launch_bounds__(256) void mha(const unsigned short* qf,
    const unsigned short* kb, const unsigned short* vb, const float* mask,
    const int* flags, float* ocat) {
  int b = blockIdx.y;
  int i0 = blockIdx.x * 16;
  int t = threadIdx.x;
  int row = t >> 4;
  int head = t & 15;
  __shared__ unsigned short Ks[CH * 16 * SEGS];  // 24 KB
  __shared__ unsigned short Vs[CH * 16 * SEGS];  // 24 KB
  __shared__ float Msk[16][CH + 1];
  float q[16];
  {
    const uint4* qp = (const uint4*)(qf + ((size_t)b * NQ + i0 + row) * DD + head * 16);
    uint4 q0 = qp[0], q1 = qp[1];
    unpack8(q0, q); unpack8(q1, q + 8);
  }
  float mmax = -INFINITY, ssum = 0.f;
  float o[16];
  #pragma unroll
  for (int d = 0; d < 16; ++d) o[d] = 0.f;

  auto body = [&](int ml) {
    const uint4* kp = (const uint4*)(&Ks[(ml * 16 + head) * SEGS]);
    uint4 ku0 = kp[0], ku1 = kp[1];
    float kf[16];
    unpack8(ku0, kf); unpack8(ku1, kf + 8);
    float s = 0.f;
    #pragma unroll
    for (int d = 0; d < 16; ++d) s = fmaf(q[d], kf[d], s);
    s = s * 0.25f + Msk[row][ml];
    float nm = fmaxf(mmax, s);
    if (nm > -INFINITY) {
      if (nm > mmax) {
        float alpha = __expf(mmax - nm);  // mmax=-inf -> 0, zeroes stale state
        ssum *= alpha;
        #pragma unroll
        for (int d = 0; d < 16; ++d) o[d] *= alpha;
        mmax = nm;
      }
      float p = __expf(s - mmax);  // s=-inf -> 0
      ssum += p;
      const uint4* vp = (const uint4*)(&Vs[(ml * 16 + head) * SEGS]);
      uint4 vu0 = vp[0], vu1 = vp[1];
      float vf[16];
      unpack8(vu0, vf); unpack8(vu1, vf + 8);
      #pragma unroll
      for (int d = 0; d < 16; ++d) o[d] = fmaf(p, vf[d], o[d]);
    }
  };

  for (int m0 = 0; m0 < NN; m0 += CH) {
    int cnt = min(CH, NN - m0);
    __syncthreads();
    int nv = cnt * 32;  // 8-short vectors in this chunk
    const uint4* gk = (const uint4*)(kb + ((size_t)b * NN + m0) * DD);
    const uint4* gv = (const uint4*)(vb + ((size_t)b * NN + m0) * DD);
    for (int vi = t; vi < nv; vi += 256) {
      int ml = vi >> 5, seg = (vi >> 1) & 15, half = vi & 1;
      int doff = (ml * 16 + seg) * SEGS + half * 8;
      *(uint4*)(&Ks[doff]) = gk[vi];
      *(uint4*)(&Vs[doff]) = gv[vi];
    }
    for (int e = t; e < 16 * CH; e += 256) {
      int r = e >> 5, ml = e & 31;
      float mv = -INFINITY;
      if (ml < cnt) {
        mv = mask[((size_t)b * NQ + i0 + r) * NN + m0 + ml];
        if ((m0 + ml) == 0 && flags[b * NQ + i0 + r]) mv = 0.f;
      }
      Msk[r][ml] = mv;
    }
    __syncthreads();
    if (cnt == CH) {
      #pragma unroll 4
      for (int ml = 0; ml < CH; ++ml) body(ml);
    } else {
      for (int ml = 0; ml < cnt; ++ml) body(ml);
    }
  }
  float inv = (ssum > 0.f) ? 1.f / ssum : 0.f;
  float* op = ocat + ((size_t)b * NQ + i0 + row) * DD + head * 16;
  #pragma unroll
  for (int d = 0; d < 16; ++d) op[d] = o[d] * inv;
}

// ---------------- combine GEMM: split-bf16 (hi+lo) MFMA, fp32-accurate ----------------
__global__ __launch_bounds__(256) void comb(const float* ocat,
    const unsigned short* WcThi, const unsigned short* WcTlo,
    const float* bc, float* mhf) {
  int wave = threadIdx.x >> 6, lane = threadIdx.x & 63;
  int quad = lane >> 4, r16 = lane & 15;
  int mbase = blockIdx.x * 64 + wave * 16;  // global row in [B*NQ]
  const float* ap = ocat + (size_t)(mbase + r16) * DD;
  int colbase = blockIdx.y * 64;
  floatx4 acc[4];
  #pragma unroll
  for (int s = 0; s < 4; ++s) {
    #pragma unroll
    for (int r = 0; r < 4; ++r) acc[s][r] = 0.f;
  }
  for (int kk = 0; kk < DD; kk += 32) {
    int k0 = kk + quad * 8;
    float4 f0 = *(const float4*)(ap + k0);
    float4 f1 = *(const float4*)(ap + k0 + 4);
    float xs[8] = {f0.x, f0.y, f0.z, f0.w, f1.x, f1.y, f1.z, f1.w};
    bf16x8 ahi, alo;
    #pragma unroll
    for (int j = 0; j < 8; ++j) {
      __bf16 h = (__bf16)xs[j];
      ahi[j] = h;
      alo[j] = (__bf16)(xs[j] - (float)h);
    }
    #pragma unroll
    for (int s = 0; s < 4; ++s) {
      int col = colbase + s * 16 + r16;
      bf16x8 whi = *(const bf16x8*)(WcThi + col * DD + k0);
      bf16x8 wlo = *(const bf16x8*)(WcTlo + col * DD + k0);
      acc[s] = __builtin_amdgcn_mfma_f32_16x16x32_bf16(ahi, whi, acc[s], 0, 0, 0);
      acc[s] = __builtin_amdgcn_mfma_f32_16x16x32_bf16(alo, whi, acc[s], 0, 0, 0);
      acc[s] = __builtin_amdgcn_mfma_f32_16x16x32_bf16(ahi, wlo, acc[s], 0, 0, 0);
    }
  }
  #pragma unroll
  for (int s = 0; s < 4; ++s) {
    #pragma unroll
    for (int r = 0; r < 4; ++r) {
      int rowg = mbase + quad * 4 + r;
      int col = colbase + s * 16 + r16;
      mhf[(size_t)rowg * DD + col] = acc[s][r] + bc[col];
    }
  }
}

// ---------------- final score2 + tanh clip + masked softmax (all fp32) ----------------
__global__ __launch_bounds__(256) void final_probs(const float* mhf,
    const float* nodes, const float* mask, const int* flags, float* out) {
  int b = blockIdx.y;
  int wave = threadIdx.x >> 6, lane = threadIdx.x & 63;
  int i = blockIdx.x * 4 + wave;
  __shared__ float mhs[4][256];
  __shared__ float scl[4][1000];
  const float4* mp = (const float4*)(mhf + ((size_t)b * NQ + i) * DD);
  ((float4*)mhs[wave])[lane] = mp[lane];
  __syncthreads();
  const float* nb = nodes + (size_t)b * NN * DD;
  const float* mkp = mask + ((size_t)b * NQ + i) * NN;
  int flag = flags[b * NQ + i];
  const float* mrow = mhs[wave];
  float pmax = -INFINITY;
  for (int m = lane; m < NN; m += 64) {
    const float4* nr = (const float4*)(nb + (size_t)m * DD);
    float acc = 0.f;
    #pragma unroll
    for (int c = 0; c < 64; ++c) {
      float4 u = nr[c];
      acc = fmaf(mrow[c * 4 + 0], u.x, acc);
      acc = fmaf(mrow[c * 4 + 1], u.y, acc);
      acc = fmaf(mrow[c * 4 + 2], u.z, acc);
      acc = fmaf(mrow[c * 4 + 3], u.w, acc);
    }
    float s = 10.f * tanhf(acc * 0.0625f);
    float mv = mkp[m];
    if (m == 0 && flag) mv = 0.f;
    s += mv;
    scl[wave][m] = s;
    pmax = fmaxf(pmax, s);
  }
  #pragma unroll
  for (int off = 32; off; off >>= 1) pmax = fmaxf(pmax, __shfl_xor(pmax, off, 64));
  float psum = 0.f;
  for (int m = lane; m < NN; m += 64) {
    float e = __expf(scl[wave][m] - pmax);
    scl[wave][m] = e;
    psum += e;
  }
  #pragma unroll
  for (int off = 32; off; off >>= 1) psum += __shfl_xor(psum, off, 64);
  float inv = 1.f / psum;
  float* op = out + ((size_t)b * NQ + i) * NN;
  for (int m = lane; m < NN; m += 64) op[m] = scl[wave][m] * inv;
}

extern "C" void kernel_launch(void* const* d_in, const int* in_sizes, int n_in,
                              void* d_out, int out_size, void* d_ws, size_t ws_size,
                              hipStream_t stream) {
  const float* eln   = (const float*)d_in[0];  // [B,n,256]
  const float* attr  = (const float*)d_in[1];  // [B,n,1]
  const float* mask  = (const float*)d_in[2];  // [B,n,N]
  const float* nodes = (const float*)d_in[3];  // [B,N,256]
  const float* Wq    = (const float*)d_in[4];  // [257,256]
  const float* Wk    = (const float*)d_in[5];
  const float* Wv    = (const float*)d_in[6];
  const float* Wc    = (const float*)d_in[7];
  const float* bc    = (const float*)d_in[8];
  float* out = (float*)d_out;

  char* ws = (char*)d_ws;
  unsigned short* kb    = (unsigned short*)(ws);              // 32,768,000 B (bf16)
  unsigned short* vb    = (unsigned short*)(ws + 32768000);   // 32,768,000 B (bf16)
  float* ocat           = (float*)(ws + 65536000);            // 33,554,432 B (fp32)
  unsigned short* qf    = (unsigned short*)(ws + 99090432);   // 16,777,216 B (bf16)
  unsigned short* WkT   = (unsigned short*)(ws + 115867648);  // 5 x 131,072 B
  unsigned short* WvT   = WkT + 65536;
  unsigned short* WqT   = WvT + 65536;
  unsigned short* WcThi = WqT + 65536;
  unsigned short* WcTlo = WcThi + 65536;
  int* flags            = (int*)(ws + 116523008);             // 131,072 B
  float* mhf = (float*)ws;  // aliases kb+vb (dead after mha); 33,554,432 B

  hipLaunchKernelGGL(transpose_w, dim3(256, 4), dim3(256), 0, stream,
                     Wk, Wv, Wq, Wc, WkT, WvT, WqT, WcThi, WcTlo);
  hipLaunchKernelGGL(mask_flags, dim3(NQ, BB), dim3(64), 0, stream, mask, flags);
  hipLaunchKernelGGL(kv_proj, dim3(16, 4, BB), dim3(256), 0, stream,
                     nodes, WkT, WvT, kb, vb);
  hipLaunchKernelGGL(q_proj, dim3(8, 4, BB), dim3(256), 0, stream,
                     eln, attr, WqT, Wq, qf);
  hipLaunchKernelGGL(mha, dim3(NQ / 16, BB), dim3(256), 0, stream,
                     qf, kb, vb, mask, flags, ocat);
  hipLaunchKernelGGL(comb, dim3((BB * NQ) / 64, 4), dim3(256), 0, stream,
                     ocat, WcThi, WcTlo, bc, mhf);
  hipLaunchKernelGGL(final_probs, dim3(NQ / 4, BB), dim3(256), 0, stream,
                     mhf, nodes, mask, flags, out);
}

// Round 3
// 1932.326 us; speedup vs baseline: 3.7149x; 3.7149x over previous
//
#include <hip/hip_runtime.h>
#include <hip/hip_bf16.h>

#define BB 64
#define NQ 512
#define NN 1000
#define DD 256

typedef __attribute__((ext_vector_type(8))) __bf16 bf16x8;
typedef __attribute__((ext_vector_type(4))) float floatx4;

__device__ __forceinline__ float b2f(unsigned short u) {
  return __uint_as_float(((unsigned)u) << 16);
}
__device__ __forceinline__ unsigned short f2b(float f) {
  __hip_bfloat16 h = __float2bfloat16(f);  // RNE
  return *reinterpret_cast<unsigned short*>(&h);
}
__device__ __forceinline__ void unpack8(uint4 u, float* f) {
  f[0] = __uint_as_float(u.x << 16); f[1] = __uint_as_float(u.x & 0xffff0000u);
  f[2] = __uint_as_float(u.y << 16); f[3] = __uint_as_float(u.y & 0xffff0000u);
  f[4] = __uint_as_float(u.z << 16); f[5] = __uint_as_float(u.z & 0xffff0000u);
  f[6] = __uint_as_float(u.w << 16); f[7] = __uint_as_float(u.w & 0xffff0000u);
}
// fp32 -> bf16x8 fragment (RNE), 8 contiguous floats
__device__ __forceinline__ bf16x8 cvt8(const float* p) {
  float4 f0 = *(const float4*)(p);
  float4 f1 = *(const float4*)(p + 4);
  bf16x8 a;
  a[0] = (__bf16)f0.x; a[1] = (__bf16)f0.y; a[2] = (__bf16)f0.z; a[3] = (__bf16)f0.w;
  a[4] = (__bf16)f1.x; a[5] = (__bf16)f1.y; a[6] = (__bf16)f1.z; a[7] = (__bf16)f1.w;
  return a;
}
__device__ __forceinline__ float fast_tanh(float x) {
  // tanh(x) = 1 - 2/(exp(2x)+1); exact at +-inf saturation
  float e = __expf(2.f * x);
  return 1.f - 2.f / (e + 1.f);
}

// ---------------- weight transposes fp32 -> bf16 (Wc split hi/lo) ----------------
__global__ void transpose_w(const float* Wk, const float* Wv, const float* Wq,
                            const float* Wc, unsigned short* WkT, unsigned short* WvT,
                            unsigned short* WqT, unsigned short* WcThi,
                            unsigned short* WcTlo) {
  int c = blockIdx.x;   // output row (original column)
  int k = threadIdx.x;  // 0..255
  if (blockIdx.y == 3) {
    float w = Wc[k * 256 + c];
    unsigned short h = f2b(w);
    WcThi[c * 256 + k] = h;
    WcTlo[c * 256 + k] = f2b(w - b2f(h));
    return;
  }
  const float* W; unsigned short* WT;
  switch (blockIdx.y) {
    case 0:  W = Wk; WT = WkT; break;
    case 1:  W = Wv; WT = WvT; break;
    default: W = Wq; WT = WqT; break;  // first 256 rows of [257][256]
  }
  WT[c * 256 + k] = f2b(W[k * 256 + c]);
}

// ---------------- all-inf row flags ----------------
__global__ void mask_flags(const float* mask, int* flags) {
  int i = blockIdx.x, b = blockIdx.y, lane = threadIdx.x;
  const float* mp = mask + ((size_t)b * NQ + i) * NN;
  bool allinf = true;
  for (int m = lane; m < NN; m += 64) allinf = allinf && isinf(mp[m]);
  unsigned long long bal = __ballot(allinf);
  if (lane == 0) flags[b * NQ + i] = (bal == ~0ull) ? 1 : 0;
}

// ---------------- nodes fp32 -> bf16 hi/lo split ----------------
__global__ __launch_bounds__(256) void node_split(const float* nodes,
    unsigned short* hi, unsigned short* lo) {
  size_t i = ((size_t)blockIdx.x * 256 + threadIdx.x) * 8;
  float4 f0 = *(const float4*)(nodes + i);
  float4 f1 = *(const float4*)(nodes + i + 4);
  float xs[8] = {f0.x, f0.y, f0.z, f0.w, f1.x, f1.y, f1.z, f1.w};
  unsigned short h[8], l[8];
  #pragma unroll
  for (int j = 0; j < 8; ++j) {
    h[j] = f2b(xs[j]);
    l[j] = f2b(xs[j] - b2f(h[j]));
  }
  *(uint4*)(hi + i) = *(const uint4*)h;
  *(uint4*)(lo + i) = *(const uint4*)l;
}

// ---------------- k,v projections (MFMA bf16, fp32 A converted inline) ----------------
__global__ __launch_bounds__(256) void kv_proj(const float* nodes,
    const unsigned short* WkT, const unsigned short* WvT,
    unsigned short* kb, unsigned short* vb) {
  int b = blockIdx.z;
  int wave = threadIdx.x >> 6, lane = threadIdx.x & 63;
  int quad = lane >> 4, r16 = lane & 15;
  int mbase = blockIdx.x * 64 + wave * 16;
  int arow = mbase + r16;
  const float* ap = nodes + ((size_t)b * NN + (arow < NN ? arow : 0)) * DD;
  int colbase = blockIdx.y * 64;
  floatx4 ak[4], av[4];
  #pragma unroll
  for (int s = 0; s < 4; ++s) {
    #pragma unroll
    for (int r = 0; r < 4; ++r) { ak[s][r] = 0.f; av[s][r] = 0.f; }
  }
  for (int kk = 0; kk < DD; kk += 32) {
    int k0 = kk + quad * 8;
    bf16x8 a = cvt8(ap + k0);
    #pragma unroll
    for (int s = 0; s < 4; ++s) {
      int col = colbase + s * 16 + r16;
      bf16x8 bk = *(const bf16x8*)(WkT + col * DD + k0);
      bf16x8 bv = *(const bf16x8*)(WvT + col * DD + k0);
      ak[s] = __builtin_amdgcn_mfma_f32_16x16x32_bf16(a, bk, ak[s], 0, 0, 0);
      av[s] = __builtin_amdgcn_mfma_f32_16x16x32_bf16(a, bv, av[s], 0, 0, 0);
    }
  }
  #pragma unroll
  for (int s = 0; s < 4; ++s) {
    #pragma unroll
    for (int r = 0; r < 4; ++r) {
      int row = mbase + quad * 4 + r;
      if (row < NN) {
        int col = colbase + s * 16 + r16;
        size_t o = ((size_t)b * NN + row) * DD + col;
        kb[o] = f2b(ak[s][r]);
        vb[o] = f2b(av[s][r]);
      }
    }
  }
}

// ---------------- q projection (MFMA bf16 + attr rank-1 term, bf16 out) ----------------
__global__ __launch_bounds__(256) void q_proj(const float* eln,
    const float* attr, const unsigned short* WqT, const float* Wq,
    unsigned short* qf) {
  int b = blockIdx.z;
  int wave = threadIdx.x >> 6, lane = threadIdx.x & 63;
  int quad = lane >> 4, r16 = lane & 15;
  int mbase = blockIdx.x * 64 + wave * 16;
  const float* ap = eln + ((size_t)b * NQ + mbase + r16) * DD;
  int colbase = blockIdx.y * 64;
  floatx4 acc[4];
  #pragma unroll
  for (int s = 0; s < 4; ++s) {
    #pragma unroll
    for (int r = 0; r < 4; ++r) acc[s][r] = 0.f;
  }
  for (int kk = 0; kk < DD; kk += 32) {
    int k0 = kk + quad * 8;
    bf16x8 a = cvt8(ap + k0);
    #pragma unroll
    for (int s = 0; s < 4; ++s) {
      int col = colbase + s * 16 + r16;
      bf16x8 bq = *(const bf16x8*)(WqT + col * DD + k0);
      acc[s] = __builtin_amdgcn_mfma_f32_16x16x32_bf16(a, bq, acc[s], 0, 0, 0);
    }
  }
  #pragma unroll
  for (int s = 0; s < 4; ++s) {
    #pragma unroll
    for (int r = 0; r < 4; ++r) {
      int row = mbase + quad * 4 + r;
      int col = colbase + s * 16 + r16;
      float aval = attr[b * NQ + row];
      float wq = Wq[256 * 256 + col];  // row 256 of Wq_last (fp32)
      qf[((size_t)b * NQ + row) * DD + col] = f2b(acc[s][r] + aval * wq);
    }
  }
}

// ---------------- fused MHA, fp32 online softmax (unchanged from R2) ----------------
#define CH 32
#define SEGS 24
__global__ __launch_bounds__(256) void mha(const unsigned short* qf,
    const unsigned short* kb, const unsigned short* vb, const float* mask,
    const int* flags, float* ocat) {
  int b = blockIdx.y;
  int i0 = blockIdx.x * 16;
  int t = threadIdx.x;
  int row = t >> 4;
  int head = t & 15;
  __shared__ unsigned short Ks[CH * 16 * SEGS];  // 24 KB
  __shared__ unsigned short Vs[CH * 16 * SEGS];  // 24 KB
  __shared__ float Msk[16][CH + 1];
  float q[16];
  {
    const uint4* qp = (const uint4*)(qf + ((size_t)b * NQ + i0 + row) * DD + head * 16);
    uint4 q0 = qp[0], q1 = qp[1];
    unpack8(q0, q); unpack8(q1, q + 8);
  }
  float mmax = -INFINITY, ssum = 0.f;
  float o[16];
  #pragma unroll
  for (int d = 0; d < 16; ++d) o[d] = 0.f;

  auto body = [&](int ml) {
    const uint4* kp = (const uint4*)(&Ks[(ml * 16 + head) * SEGS]);
    uint4 ku0 = kp[0], ku1 = kp[1];
    float kf[16];
    unpack8(ku0, kf); unpack8(ku1, kf + 8);
    float s = 0.f;
    #pragma unroll
    for (int d = 0; d < 16; ++d) s = fmaf(q[d], kf[d], s);
    s = s * 0.25f + Msk[row][ml];
    float nm = fmaxf(mmax, s);
    if (nm > -INFINITY) {
      if (nm > mmax) {
        float alpha = __expf(mmax - nm);
        ssum *= alpha;
        #pragma unroll
        for (int d = 0; d < 16; ++d) o[d] *= alpha;
        mmax = nm;
      }
      float p = __expf(s - mmax);
      ssum += p;
      const uint4* vp = (const uint4*)(&Vs[(ml * 16 + head) * SEGS]);
      uint4 vu0 = vp[0], vu1 = vp[1];
      float vf[16];
      unpack8(vu0, vf); unpack8(vu1, vf + 8);
      #pragma unroll
      for (int d = 0; d < 16; ++d) o[d] = fmaf(p, vf[d], o[d]);
    }
  };

  for (int m0 = 0; m0 < NN; m0 += CH) {
    int cnt = min(CH, NN - m0);
    __syncthreads();
    int nv = cnt * 32;
    const uint4* gk = (const uint4*)(kb + ((size_t)b * NN + m0) * DD);
    const uint4* gv = (const uint4*)(vb + ((size_t)b * NN + m0) * DD);
    for (int vi = t; vi < nv; vi += 256) {
      int ml = vi >> 5, seg = (vi >> 1) & 15, half = vi & 1;
      int doff = (ml * 16 + seg) * SEGS + half * 8;
      *(uint4*)(&Ks[doff]) = gk[vi];
      *(uint4*)(&Vs[doff]) = gv[vi];
    }
    for (int e = t; e < 16 * CH; e += 256) {
      int r = e >> 5, ml = e & 31;
      float mv = -INFINITY;
      if (ml < cnt) {
        mv = mask[((size_t)b * NQ + i0 + r) * NN + m0 + ml];
        if ((m0 + ml) == 0 && flags[b * NQ + i0 + r]) mv = 0.f;
      }
      Msk[r][ml] = mv;
    }
    __syncthreads();
    if (cnt == CH) {
      #pragma unroll 4
      for (int ml = 0; ml < CH; ++ml) body(ml);
    } else {
      for (int ml = 0; ml < cnt; ++ml) body(ml);
    }
  }
  float inv = (ssum > 0.f) ? 1.f / ssum : 0.f;
  float* op = ocat + ((size_t)b * NQ + i0 + row) * DD + head * 16;
  #pragma unroll
  for (int d = 0; d < 16; ++d) op[d] = o[d] * inv;
}

// ---------------- combine GEMM: split-bf16 (hi+lo) MFMA, fp32-accurate ----------------
__global__ __launch_bounds__(256) void comb(const float* ocat,
    const unsigned short* WcThi, const unsigned short* WcTlo,
    const float* bc, float* mhf) {
  int wave = threadIdx.x >> 6, lane = threadIdx.x & 63;
  int quad = lane >> 4, r16 = lane & 15;
  int mbase = blockIdx.x * 64 + wave * 16;  // global row in [B*NQ]
  const float* ap = ocat + (size_t)(mbase + r16) * DD;
  int colbase = blockIdx.y * 64;
  floatx4 acc[4];
  #pragma unroll
  for (int s = 0; s < 4; ++s) {
    #pragma unroll
    for (int r = 0; r < 4; ++r) acc[s][r] = 0.f;
  }
  for (int kk = 0; kk < DD; kk += 32) {
    int k0 = kk + quad * 8;
    float4 f0 = *(const float4*)(ap + k0);
    float4 f1 = *(const float4*)(ap + k0 + 4);
    float xs[8] = {f0.x, f0.y, f0.z, f0.w, f1.x, f1.y, f1.z, f1.w};
    bf16x8 ahi, alo;
    #pragma unroll
    for (int j = 0; j < 8; ++j) {
      __bf16 h = (__bf16)xs[j];
      ahi[j] = h;
      alo[j] = (__bf16)(xs[j] - (float)h);
    }
    #pragma unroll
    for (int s = 0; s < 4; ++s) {
      int col = colbase + s * 16 + r16;
      bf16x8 whi = *(const bf16x8*)(WcThi + col * DD + k0);
      bf16x8 wlo = *(const bf16x8*)(WcTlo + col * DD + k0);
      acc[s] = __builtin_amdgcn_mfma_f32_16x16x32_bf16(ahi, whi, acc[s], 0, 0, 0);
      acc[s] = __builtin_amdgcn_mfma_f32_16x16x32_bf16(alo, whi, acc[s], 0, 0, 0);
      acc[s] = __builtin_amdgcn_mfma_f32_16x16x32_bf16(ahi, wlo, acc[s], 0, 0, 0);
    }
  }
  #pragma unroll
  for (int s = 0; s < 4; ++s) {
    #pragma unroll
    for (int r = 0; r < 4; ++r) {
      int rowg = mbase + quad * 4 + r;
      int col = colbase + s * 16 + r16;
      mhf[(size_t)rowg * DD + col] = acc[s][r] + bc[col];
    }
  }
}

// ---------------- final: score2 via MFMA (split hi/lo) + tanh + masked softmax ----------------
// block = (b, 16 query rows). Per wave: A-frags preloaded in regs (shared rows),
// round-robin over 63 col-tiles of 16 nodes; scores in LDS; softmax epilogue.
#define SCL_STRIDE 1012
__global__ __launch_bounds__(256) void final_probs_mfma(const float* mhf,
    const unsigned short* nhi, const unsigned short* nlo,
    const float* mask, const int* flags, float* out) {
  int b = blockIdx.y;
  int i0 = blockIdx.x * 16;
  int t = threadIdx.x;
  int wave = t >> 6, lane = t & 63;
  int quad = lane >> 4, l15 = lane & 15;
  __shared__ float scl[16][SCL_STRIDE];  // 64,768 B

  // preload A fragments (mh rows i0..i0+15, split bf16 hi/lo): 64 VGPRs
  bf16x8 Ahi[8], Alo[8];
  {
    const float* ap = mhf + ((size_t)b * NQ + i0 + l15) * DD + quad * 8;
    #pragma unroll
    for (int kk = 0; kk < 8; ++kk) {
      float4 f0 = *(const float4*)(ap + kk * 32);
      float4 f1 = *(const float4*)(ap + kk * 32 + 4);
      float xs[8] = {f0.x, f0.y, f0.z, f0.w, f1.x, f1.y, f1.z, f1.w};
      #pragma unroll
      for (int j = 0; j < 8; ++j) {
        __bf16 h = (__bf16)xs[j];
        Ahi[kk][j] = h;
        Alo[kk][j] = (__bf16)(xs[j] - (float)h);
      }
    }
  }
  // GEMM: wave handles col-tiles wave, wave+4, ... (63 tiles cover cols 0..1007;
  // cols >=1000 are garbage, never read by the epilogue)
  const unsigned short* bh0 = nhi + ((size_t)b * NN + l15) * DD + quad * 8;
  const unsigned short* bl0 = nlo + ((size_t)b * NN + l15) * DD + quad * 8;
  for (int tile = wave; tile < 63; tile += 4) {
    int n0 = tile * 16;
    const unsigned short* bh = bh0 + (size_t)n0 * DD;
    const unsigned short* bl = bl0 + (size_t)n0 * DD;
    floatx4 acc = {0.f, 0.f, 0.f, 0.f};
    #pragma unroll
    for (int kk = 0; kk < 8; ++kk) {
      bf16x8 Bh = *(const bf16x8*)(bh + kk * 32);
      bf16x8 Bl = *(const bf16x8*)(bl + kk * 32);
      acc = __builtin_amdgcn_mfma_f32_16x16x32_bf16(Ahi[kk], Bh, acc, 0, 0, 0);
      acc = __builtin_amdgcn_mfma_f32_16x16x32_bf16(Alo[kk], Bh, acc, 0, 0, 0);
      acc = __builtin_amdgcn_mfma_f32_16x16x32_bf16(Ahi[kk], Bl, acc, 0, 0, 0);
    }
    #pragma unroll
    for (int r = 0; r < 4; ++r) scl[quad * 4 + r][n0 + l15] = acc[r];
  }
  __syncthreads();

  // softmax epilogue: wave w handles rows 4w..4w+3
  const float* mkp = mask + ((size_t)b * NQ + i0) * NN;
  float* op = out + ((size_t)b * NQ + i0) * NN;
  for (int rr = 0; rr < 4; ++rr) {
    int row = wave * 4 + rr;
    int flag = flags[b * NQ + i0 + row];
    const float* mrow = mkp + (size_t)row * NN;
    float pmax = -INFINITY;
    for (int c = lane; c < NN; c += 64) {
      float s = 10.f * fast_tanh(scl[row][c] * 0.0625f);
      float mv = mrow[c];
      if (c == 0 && flag) mv = 0.f;
      s += mv;
      scl[row][c] = s;
      pmax = fmaxf(pmax, s);
    }
    #pragma unroll
    for (int off = 32; off; off >>= 1) pmax = fmaxf(pmax, __shfl_xor(pmax, off, 64));
    float psum = 0.f;
    for (int c = lane; c < NN; c += 64) {
      float e = __expf(scl[row][c] - pmax);
      scl[row][c] = e;
      psum += e;
    }
    #pragma unroll
    for (int off = 32; off; off >>= 1) psum += __shfl_xor(psum, off, 64);
    float inv = 1.f / psum;
    for (int c = lane; c < NN; c += 64) op[(size_t)row * NN + c] = scl[row][c] * inv;
  }
}

extern "C" void kernel_launch(void* const* d_in, const int* in_sizes, int n_in,
                              void* d_out, int out_size, void* d_ws, size_t ws_size,
                              hipStream_t stream) {
  const float* eln   = (const float*)d_in[0];  // [B,n,256]
  const float* attr  = (const float*)d_in[1];  // [B,n,1]
  const float* mask  = (const float*)d_in[2];  // [B,n,N]
  const float* nodes = (const float*)d_in[3];  // [B,N,256]
  const float* Wq    = (const float*)d_in[4];  // [257,256]
  const float* Wk    = (const float*)d_in[5];
  const float* Wv    = (const float*)d_in[6];
  const float* Wc    = (const float*)d_in[7];
  const float* bc    = (const float*)d_in[8];
  float* out = (float*)d_out;

  char* ws = (char*)d_ws;
  unsigned short* kb    = (unsigned short*)(ws);              // 32,768,000 B (bf16)
  unsigned short* vb    = (unsigned short*)(ws + 32768000);   // 32,768,000 B (bf16)
  float* ocat           = (float*)(ws + 65536000);            // 33,554,432 B (fp32)
  unsigned short* qf    = (unsigned short*)(ws + 99090432);   // 16,777,216 B (bf16)
  unsigned short* WkT   = (unsigned short*)(ws + 115867648);  // 5 x 131,072 B
  unsigned short* WvT   = WkT + 65536;
  unsigned short* WqT   = WvT + 65536;
  unsigned short* WcThi = WqT + 65536;
  unsigned short* WcTlo = WcThi + 65536;
  int* flags            = (int*)(ws + 116523008);             // 131,072 B
  // aliased (dead-after-mha/comb regions):
  float* mhf          = (float*)ws;                           // 33,554,432 B over kb/vb
  unsigned short* nhi = (unsigned short*)(ws + 41943040);     // 32,776,192 B over vb/ocat
  unsigned short* nlo = (unsigned short*)(ws + 74719232);     // 32,776,192 B over ocat/qf

  hipLaunchKernelGGL(transpose_w, dim3(256, 4), dim3(256), 0, stream,
                     Wk, Wv, Wq, Wc, WkT, WvT, WqT, WcThi, WcTlo);
  hipLaunchKernelGGL(mask_flags, dim3(NQ, BB), dim3(64), 0, stream, mask, flags);
  hipLaunchKernelGGL(kv_proj, dim3(16, 4, BB), dim3(256), 0, stream,
                     nodes, WkT, WvT, kb, vb);
  hipLaunchKernelGGL(q_proj, dim3(8, 4, BB), dim3(256), 0, stream,
                     eln, attr, WqT, Wq, qf);
  hipLaunchKernelGGL(mha, dim3(NQ / 16, BB), dim3(256), 0, stream,
                     qf, kb, vb, mask, flags, ocat);
  hipLaunchKernelGGL(comb, dim3((BB * NQ) / 64, 4), dim3(256), 0, stream,
                     ocat, WcThi, WcTlo, bc, mhf);
  hipLaunchKernelGGL(node_split, dim3(8000), dim3(256), 0, stream, nodes, nhi, nlo);
  hipLaunchKernelGGL(final_probs_mfma, dim3(NQ / 16, BB), dim3(256), 0, stream,
                     mhf, nhi, nlo, mask, flags, out);
}

// Round 4
// 1304.828 us; speedup vs baseline: 5.5014x; 1.4809x over previous
//
#include <hip/hip_runtime.h>
#include <hip/hip_bf16.h>

#define BB 64
#define NQ 512
#define NN 1000
#define DD 256
#define NP 1008  // vbT padded node stride

typedef __attribute__((ext_vector_type(8))) __bf16 bf16x8;
typedef __attribute__((ext_vector_type(4))) float floatx4;

__device__ __forceinline__ float b2f(unsigned short u) {
  return __uint_as_float(((unsigned)u) << 16);
}
__device__ __forceinline__ unsigned short f2b(float f) {
  __hip_bfloat16 h = __float2bfloat16(f);  // RNE
  return *reinterpret_cast<unsigned short*>(&h);
}
__device__ __forceinline__ float fast_tanh(float x) {
  float e = __expf(2.f * x);
  return 1.f - 2.f / (e + 1.f);
}
// fp32 -> bf16x8 fragment (RNE), 8 contiguous floats
__device__ __forceinline__ bf16x8 cvt8(const float* p) {
  float4 f0 = *(const float4*)(p);
  float4 f1 = *(const float4*)(p + 4);
  bf16x8 a;
  a[0] = (__bf16)f0.x; a[1] = (__bf16)f0.y; a[2] = (__bf16)f0.z; a[3] = (__bf16)f0.w;
  a[4] = (__bf16)f1.x; a[5] = (__bf16)f1.y; a[6] = (__bf16)f1.z; a[7] = (__bf16)f1.w;
  return a;
}

// ---------------- weight transposes fp32 -> bf16 (Wc split hi/lo) ----------------
__global__ void transpose_w(const float* Wk, const float* Wv, const float* Wq,
                            const float* Wc, unsigned short* WkT, unsigned short* WvT,
                            unsigned short* WqT, unsigned short* WcThi,
                            unsigned short* WcTlo) {
  int c = blockIdx.x;
  int k = threadIdx.x;
  if (blockIdx.y == 3) {
    float w = Wc[k * 256 + c];
    unsigned short h = f2b(w);
    WcThi[c * 256 + k] = h;
    WcTlo[c * 256 + k] = f2b(w - b2f(h));
    return;
  }
  const float* W; unsigned short* WT;
  switch (blockIdx.y) {
    case 0:  W = Wk; WT = WkT; break;
    case 1:  W = Wv; WT = WvT; break;
    default: W = Wq; WT = WqT; break;
  }
  WT[c * 256 + k] = f2b(W[k * 256 + c]);
}

// ---------------- all-inf row flags ----------------
__global__ void mask_flags(const float* mask, int* flags) {
  int i = blockIdx.x, b = blockIdx.y, lane = threadIdx.x;
  const float* mp = mask + ((size_t)b * NQ + i) * NN;
  bool allinf = true;
  for (int m = lane; m < NN; m += 64) allinf = allinf && isinf(mp[m]);
  unsigned long long bal = __ballot(allinf);
  if (lane == 0) flags[b * NQ + i] = (bal == ~0ull) ? 1 : 0;
}

// ---------------- nodes fp32 -> bf16 hi/lo split ----------------
__global__ __launch_bounds__(256) void node_split(const float* nodes,
    unsigned short* hi, unsigned short* lo) {
  size_t i = ((size_t)blockIdx.x * 256 + threadIdx.x) * 8;
  float4 f0 = *(const float4*)(nodes + i);
  float4 f1 = *(const float4*)(nodes + i + 4);
  float xs[8] = {f0.x, f0.y, f0.z, f0.w, f1.x, f1.y, f1.z, f1.w};
  unsigned short h[8], l[8];
  #pragma unroll
  for (int j = 0; j < 8; ++j) {
    h[j] = f2b(xs[j]);
    l[j] = f2b(xs[j] - b2f(h[j]));
  }
  *(uint4*)(hi + i) = *(const uint4*)h;
  *(uint4*)(lo + i) = *(const uint4*)l;
}

// ---------------- k,v projections: kb [b][node][h*16+d], vbT [b][h][d][node(1008)] ----------------
__global__ __launch_bounds__(256) void kv_proj(const float* nodes,
    const unsigned short* WkT, const unsigned short* WvT,
    unsigned short* kb, unsigned short* vbT) {
  int b = blockIdx.z;
  int wave = threadIdx.x >> 6, lane = threadIdx.x & 63;
  int quad = lane >> 4, r16 = lane & 15;
  int mbase = blockIdx.x * 64 + wave * 16;
  int arow = mbase + r16;
  const float* ap = nodes + ((size_t)b * NN + (arow < NN ? arow : 0)) * DD;
  int colbase = blockIdx.y * 64;
  floatx4 ak[4], av[4];
  #pragma unroll
  for (int s = 0; s < 4; ++s) {
    #pragma unroll
    for (int r = 0; r < 4; ++r) { ak[s][r] = 0.f; av[s][r] = 0.f; }
  }
  for (int kk = 0; kk < DD; kk += 32) {
    int k0 = kk + quad * 8;
    bf16x8 a = cvt8(ap + k0);
    #pragma unroll
    for (int s = 0; s < 4; ++s) {
      int col = colbase + s * 16 + r16;
      bf16x8 bk = *(const bf16x8*)(WkT + col * DD + k0);
      bf16x8 bv = *(const bf16x8*)(WvT + col * DD + k0);
      ak[s] = __builtin_amdgcn_mfma_f32_16x16x32_bf16(a, bk, ak[s], 0, 0, 0);
      av[s] = __builtin_amdgcn_mfma_f32_16x16x32_bf16(a, bv, av[s], 0, 0, 0);
    }
  }
  #pragma unroll
  for (int s = 0; s < 4; ++s) {
    #pragma unroll
    for (int r = 0; r < 4; ++r) {
      int row = mbase + quad * 4 + r;
      int col = colbase + s * 16 + r16;
      if (row < NN) {
        kb[((size_t)b * NN + row) * DD + col] = f2b(ak[s][r]);
      }
      if (row < NP) {
        int h = col >> 4, d = col & 15;
        vbT[(((size_t)b * 16 + h) * 16 + d) * NP + row] =
            f2b(row < NN ? av[s][r] : 0.f);
      }
    }
  }
}

// ---------------- q projection (MFMA bf16 + attr rank-1 term, bf16 out) ----------------
__global__ __launch_bounds__(256) void q_proj(const float* eln,
    const float* attr, const unsigned short* WqT, const float* Wq,
    unsigned short* qf) {
  int b = blockIdx.z;
  int wave = threadIdx.x >> 6, lane = threadIdx.x & 63;
  int quad = lane >> 4, r16 = lane & 15;
  int mbase = blockIdx.x * 64 + wave * 16;
  const float* ap = eln + ((size_t)b * NQ + mbase + r16) * DD;
  int colbase = blockIdx.y * 64;
  floatx4 acc[4];
  #pragma unroll
  for (int s = 0; s < 4; ++s) {
    #pragma unroll
    for (int r = 0; r < 4; ++r) acc[s][r] = 0.f;
  }
  for (int kk = 0; kk < DD; kk += 32) {
    int k0 = kk + quad * 8;
    bf16x8 a = cvt8(ap + k0);
    #pragma unroll
    for (int s = 0; s < 4; ++s) {
      int col = colbase + s * 16 + r16;
      bf16x8 bq = *(const bf16x8*)(WqT + col * DD + k0);
      acc[s] = __builtin_amdgcn_mfma_f32_16x16x32_bf16(a, bq, acc[s], 0, 0, 0);
    }
  }
  #pragma unroll
  for (int s = 0; s < 4; ++s) {
    #pragma unroll
    for (int r = 0; r < 4; ++r) {
      int row = mbase + quad * 4 + r;
      int col = colbase + s * 16 + r16;
      float aval = attr[b * NQ + row];
      float wq = Wq[256 * 256 + col];
      qf[((size_t)b * NQ + row) * DD + col] = f2b(acc[s][r] + aval * wq);
    }
  }
}

// ---------------- MFMA flash attention ----------------
// block = (qtile of 64, head, batch); 4 waves, wave = 16 queries, loops all nodes.
// S^T = K*Q^T via 16x16x32 (dk=16 zero-padded): C gives query=lane&15, node=quad*4+reg
//   -> softmax reduction = 4 in-lane + shfl_xor(16,32).
// P^T staged in LDS (hi/lo bf16 split, fp32-exact weights), chained as B-operand of
// O^T = V^T*P^T (K=32 nodes fully used). No __syncthreads (intra-wave LDS only).
#define L2E 1.44269504f
__global__ __launch_bounds__(256) void mha_mfma(const unsigned short* qf,
    const unsigned short* kb, const unsigned short* vbT, const float* mask,
    const int* flags, float* ocat) {
  int b = blockIdx.z;
  int h = blockIdx.y;
  int wv = threadIdx.x >> 6;
  int lane = threadIdx.x & 63;
  int quad = lane >> 4, l15 = lane & 15;
  int q0 = blockIdx.x * 64 + wv * 16;
  __shared__ __align__(16) unsigned short Pst[4][2][640];  // [wave][hi/lo][16q x 40]

  bf16x8 zero8;
  #pragma unroll
  for (int j = 0; j < 8; ++j) zero8[j] = (__bf16)0.0f;

  // Q fragment (B operand): B[col=q=l15][k=d=quad*8+j]; k>=16 (quads 2,3) zero
  bf16x8 Qf = zero8;
  if (quad < 2)
    Qf = *(const bf16x8*)(qf + ((size_t)(b * NQ + q0 + l15)) * DD + h * 16 + quad * 8);

  int flag = flags[b * NQ + q0 + l15];
  const float* mrow = mask + ((size_t)(b * NQ + q0 + l15)) * NN;
  const unsigned short* kbase = kb + ((size_t)b * NN) * DD + h * 16;
  const unsigned short* vbase = vbT + (((size_t)b * 16 + h) * 16 + l15) * NP;
  unsigned short* pwh = &Pst[wv][0][l15 * 40];
  unsigned short* pwl = &Pst[wv][1][l15 * 40];

  float m = -INFINITY, l = 0.f;
  floatx4 o = {0.f, 0.f, 0.f, 0.f};
  const float4 ninf4 = make_float4(-INFINITY, -INFINITY, -INFINITY, -INFINITY);
  const float sc = 0.25f * L2E;  // exp2 domain

  for (int c = 0; c < 32; ++c) {
    int n0 = c * 32;
    // K fragments (A operand): A[row=node][k=d], quads 2,3 zero; tail predicated
    int na = n0 + l15, nb = n0 + 16 + l15;
    bf16x8 Ka = (quad < 2 && na < NN)
        ? *(const bf16x8*)(kbase + (size_t)na * DD + quad * 8) : zero8;
    bf16x8 Kb = (quad < 2 && nb < NN)
        ? *(const bf16x8*)(kbase + (size_t)nb * DD + quad * 8) : zero8;
    floatx4 z4 = {0.f, 0.f, 0.f, 0.f};
    floatx4 sa = __builtin_amdgcn_mfma_f32_16x16x32_bf16(Ka, Qf, z4, 0, 0, 0);
    floatx4 sb = __builtin_amdgcn_mfma_f32_16x16x32_bf16(Kb, Qf, z4, 0, 0, 0);
    // masks (node-contiguous float4 per lane), log2-domain
    int nma = n0 + quad * 4, nmb = n0 + 16 + quad * 4;
    float4 ma = (nma < NN) ? *(const float4*)(mrow + nma) : ninf4;
    float4 mb = (nmb < NN) ? *(const float4*)(mrow + nmb) : ninf4;
    if (flag && c == 0 && quad == 0) ma.x = 0.f;  // all-inf row fix (node 0)
    float s[8];
    s[0] = sa[0] * sc + ma.x * L2E; s[1] = sa[1] * sc + ma.y * L2E;
    s[2] = sa[2] * sc + ma.z * L2E; s[3] = sa[3] * sc + ma.w * L2E;
    s[4] = sb[0] * sc + mb.x * L2E; s[5] = sb[1] * sc + mb.y * L2E;
    s[6] = sb[2] * sc + mb.z * L2E; s[7] = sb[3] * sc + mb.w * L2E;
    // chunk max per query (in-lane 8 + cross-quad shuffles)
    float cm = s[0];
    #pragma unroll
    for (int i = 1; i < 8; ++i) cm = fmaxf(cm, s[i]);
    cm = fmaxf(cm, __shfl_xor(cm, 16, 64));
    cm = fmaxf(cm, __shfl_xor(cm, 32, 64));
    float nm = fmaxf(m, cm);
    float nme = fmaxf(nm, -1e30f);
    float alpha = exp2f(m - nme);  // m=-inf -> 0
    float p[8];
    #pragma unroll
    for (int i = 0; i < 8; ++i) p[i] = exp2f(s[i] - nme);
    // split p hi/lo (fp32-exact PV weights), sum in fp32
    unsigned short ph[8], pl[8];
    float ps = 0.f;
    #pragma unroll
    for (int i = 0; i < 8; ++i) {
      ph[i] = f2b(p[i]);
      float hv = b2f(ph[i]);
      pl[i] = f2b(p[i] - hv);
      ps += p[i];
    }
    ps += __shfl_xor(ps, 16, 64);
    ps += __shfl_xor(ps, 32, 64);
    l = l * alpha + ps;
    m = nm;
    #pragma unroll
    for (int r = 0; r < 4; ++r) o[r] *= alpha;
    // stage P^T: k slot = node-in-chunk; tile0 -> quad*4, tile1 -> 16+quad*4
    *(uint2*)(pwh + quad * 4)      = *(const uint2*)(ph + 0);
    *(uint2*)(pwh + 16 + quad * 4) = *(const uint2*)(ph + 4);
    *(uint2*)(pwl + quad * 4)      = *(const uint2*)(pl + 0);
    *(uint2*)(pwl + 16 + quad * 4) = *(const uint2*)(pl + 4);
    // V^T fragment (A operand): A[row=d=l15][k=node=quad*8+j]
    int nv = n0 + quad * 8;
    bf16x8 Vf = (nv < NP) ? *(const bf16x8*)(vbase + nv) : zero8;
    // P^T fragments (B operand): B[col=q=l15][k=quad*8+j]  (intra-wave LDS, in-order)
    bf16x8 Phi = *(const bf16x8*)(&Pst[wv][0][l15 * 40] + quad * 8);
    bf16x8 Plo = *(const bf16x8*)(&Pst[wv][1][l15 * 40] + quad * 8);
    o = __builtin_amdgcn_mfma_f32_16x16x32_bf16(Vf, Phi, o, 0, 0, 0);
    o = __builtin_amdgcn_mfma_f32_16x16x32_bf16(Vf, Plo, o, 0, 0, 0);
  }
  float inv = (l > 0.f) ? 1.f / l : 0.f;
  float4 ov = make_float4(o[0] * inv, o[1] * inv, o[2] * inv, o[3] * inv);
  *(float4*)(ocat + ((size_t)(b * NQ + q0 + l15)) * DD + h * 16 + quad * 4) = ov;
}

// ---------------- combine GEMM: split-bf16 (hi+lo) MFMA, fp32-accurate ----------------
__global__ __launch_bounds__(256) void comb(const float* ocat,
    const unsigned short* WcThi, const unsigned short* WcTlo,
    const float* bc, float* mhf) {
  int wave = threadIdx.x >> 6, lane = threadIdx.x & 63;
  int quad = lane >> 4, r16 = lane & 15;
  int mbase = blockIdx.x * 64 + wave * 16;
  const float* ap = ocat + (size_t)(mbase + r16) * DD;
  int colbase = blockIdx.y * 64;
  floatx4 acc[4];
  #pragma unroll
  for (int s = 0; s < 4; ++s) {
    #pragma unroll
    for (int r = 0; r < 4; ++r) acc[s][r] = 0.f;
  }
  for (int kk = 0; kk < DD; kk += 32) {
    int k0 = kk + quad * 8;
    float4 f0 = *(const float4*)(ap + k0);
    float4 f1 = *(const float4*)(ap + k0 + 4);
    float xs[8] = {f0.x, f0.y, f0.z, f0.w, f1.x, f1.y, f1.z, f1.w};
    bf16x8 ahi, alo;
    #pragma unroll
    for (int j = 0; j < 8; ++j) {
      __bf16 hh = (__bf16)xs[j];
      ahi[j] = hh;
      alo[j] = (__bf16)(xs[j] - (float)hh);
    }
    #pragma unroll
    for (int s = 0; s < 4; ++s) {
      int col = colbase + s * 16 + r16;
      bf16x8 whi = *(const bf16x8*)(WcThi + col * DD + k0);
      bf16x8 wlo = *(const bf16x8*)(WcTlo + col * DD + k0);
      acc[s] = __builtin_amdgcn_mfma_f32_16x16x32_bf16(ahi, whi, acc[s], 0, 0, 0);
      acc[s] = __builtin_amdgcn_mfma_f32_16x16x32_bf16(alo, whi, acc[s], 0, 0, 0);
      acc[s] = __builtin_amdgcn_mfma_f32_16x16x32_bf16(ahi, wlo, acc[s], 0, 0, 0);
    }
  }
  #pragma unroll
  for (int s = 0; s < 4; ++s) {
    #pragma unroll
    for (int r = 0; r < 4; ++r) {
      int rowg = mbase + quad * 4 + r;
      int col = colbase + s * 16 + r16;
      mhf[(size_t)rowg * DD + col] = acc[s][r] + bc[col];
    }
  }
}

// ---------------- final: score2 via MFMA (split hi/lo) + tanh + masked softmax ----------------
#define SCL_STRIDE 1012
__global__ __launch_bounds__(256) void final_probs_mfma(const float* mhf,
    const unsigned short* nhi, const unsigned short* nlo,
    const float* mask, const int* flags, float* out) {
  int b = blockIdx.y;
  int i0 = blockIdx.x * 16;
  int t = threadIdx.x;
  int wave = t >> 6, lane = t & 63;
  int quad = lane >> 4, l15 = lane & 15;
  __shared__ float scl[16][SCL_STRIDE];  // 64,768 B

  bf16x8 Ahi[8], Alo[8];
  {
    const float* ap = mhf + ((size_t)b * NQ + i0 + l15) * DD + quad * 8;
    #pragma unroll
    for (int kk = 0; kk < 8; ++kk) {
      float4 f0 = *(const float4*)(ap + kk * 32);
      float4 f1 = *(const float4*)(ap + kk * 32 + 4);
      float xs[8] = {f0.x, f0.y, f0.z, f0.w, f1.x, f1.y, f1.z, f1.w};
      #pragma unroll
      for (int j = 0; j < 8; ++j) {
        __bf16 hh = (__bf16)xs[j];
        Ahi[kk][j] = hh;
        Alo[kk][j] = (__bf16)(xs[j] - (float)hh);
      }
    }
  }
  const unsigned short* bh0 = nhi + ((size_t)b * NN + l15) * DD + quad * 8;
  const unsigned short* bl0 = nlo + ((size_t)b * NN + l15) * DD + quad * 8;
  for (int tile = wave; tile < 63; tile += 4) {
    int n0 = tile * 16;
    const unsigned short* bh = bh0 + (size_t)n0 * DD;
    const unsigned short* bl = bl0 + (size_t)n0 * DD;
    floatx4 acc = {0.f, 0.f, 0.f, 0.f};
    #pragma unroll
    for (int kk = 0; kk < 8; ++kk) {
      bf16x8 Bh = *(const bf16x8*)(bh + kk * 32);
      bf16x8 Bl = *(const bf16x8*)(bl + kk * 32);
      acc = __builtin_amdgcn_mfma_f32_16x16x32_bf16(Ahi[kk], Bh, acc, 0, 0, 0);
      acc = __builtin_amdgcn_mfma_f32_16x16x32_bf16(Alo[kk], Bh, acc, 0, 0, 0);
      acc = __builtin_amdgcn_mfma_f32_16x16x32_bf16(Ahi[kk], Bl, acc, 0, 0, 0);
    }
    #pragma unroll
    for (int r = 0; r < 4; ++r) scl[quad * 4 + r][n0 + l15] = acc[r];
  }
  __syncthreads();

  const float* mkp = mask + ((size_t)b * NQ + i0) * NN;
  float* op = out + ((size_t)b * NQ + i0) * NN;
  for (int rr = 0; rr < 4; ++rr) {
    int row = wave * 4 + rr;
    int flag = flags[b * NQ + i0 + row];
    const float* mrow = mkp + (size_t)row * NN;
    float pmax = -INFINITY;
    for (int c = lane; c < NN; c += 64) {
      float s = 10.f * fast_tanh(scl[row][c] * 0.0625f);
      float mv = mrow[c];
      if (c == 0 && flag) mv = 0.f;
      s += mv;
      scl[row][c] = s;
      pmax = fmaxf(pmax, s);
    }
    #pragma unroll
    for (int off = 32; off; off >>= 1) pmax = fmaxf(pmax, __shfl_xor(pmax, off, 64));
    float psum = 0.f;
    for (int c = lane; c < NN; c += 64) {
      float e = __expf(scl[row][c] - pmax);
      scl[row][c] = e;
      psum += e;
    }
    #pragma unroll
    for (int off = 32; off; off >>= 1) psum += __shfl_xor(psum, off, 64);
    float inv = 1.f / psum;
    for (int c = lane; c < NN; c += 64) op[(size_t)row * NN + c] = scl[row][c] * inv;
  }
}

extern "C" void kernel_launch(void* const* d_in, const int* in_sizes, int n_in,
                              void* d_out, int out_size, void* d_ws, size_t ws_size,
                              hipStream_t stream) {
  const float* eln   = (const float*)d_in[0];  // [B,n,256]
  const float* attr  = (const float*)d_in[1];  // [B,n,1]
  const float* mask  = (const float*)d_in[2];  // [B,n,N]
  const float* nodes = (const float*)d_in[3];  // [B,N,256]
  const float* Wq    = (const float*)d_in[4];  // [257,256]
  const float* Wk    = (const float*)d_in[5];
  const float* Wv    = (const float*)d_in[6];
  const float* Wc    = (const float*)d_in[7];
  const float* bc    = (const float*)d_in[8];
  float* out = (float*)d_out;

  char* ws = (char*)d_ws;
  // phase-1 live set (through mha): kb, vbT, ocat, qf, WcT*, flags
  unsigned short* kb    = (unsigned short*)(ws);               // 32,768,000 B
  unsigned short* vbT   = (unsigned short*)(ws + 32768000);    // 33,030,144 B
  float* ocat           = (float*)(ws + 65798144);             // 33,554,432 B
  unsigned short* qf    = (unsigned short*)(ws + 99352576);    // 16,777,216 B
  unsigned short* WcThi = (unsigned short*)(ws + 116129792);   // 131,072 B
  unsigned short* WcTlo = (unsigned short*)(ws + 116260864);   // 131,072 B
  int* flags            = (int*)(ws + 116391936);              // 131,072 B -> 116,523,008 total
  // k/v/q transposed weights live inside the (not-yet-written) ocat region
  unsigned short* WkT   = (unsigned short*)(ws + 65798144);
  unsigned short* WvT   = WkT + 65536;
  unsigned short* WqT   = WvT + 65536;
  // phase-2 aliases (after mha / comb):
  float* mhf          = (float*)ws;                            // 33,554,432 B over kb+vbT
  unsigned short* nhi = (unsigned short*)(ws + 33554432);      // 32,768,000 B over vbT/ocat
  unsigned short* nlo = (unsigned short*)(ws + 66322432);      // 32,768,000 B over ocat/qf

  hipLaunchKernelGGL(transpose_w, dim3(256, 4), dim3(256), 0, stream,
                     Wk, Wv, Wq, Wc, WkT, WvT, WqT, WcThi, WcTlo);
  hipLaunchKernelGGL(mask_flags, dim3(NQ, BB), dim3(64), 0, stream, mask, flags);
  hipLaunchKernelGGL(kv_proj, dim3(16, 4, BB), dim3(256), 0, stream,
                     nodes, WkT, WvT, kb, vbT);
  hipLaunchKernelGGL(q_proj, dim3(8, 4, BB), dim3(256), 0, stream,
                     eln, attr, WqT, Wq, qf);
  hipLaunchKernelGGL(mha_mfma, dim3(8, 16, BB), dim3(256), 0, stream,
                     qf, kb, vbT, mask, flags, ocat);
  hipLaunchKernelGGL(comb, dim3((BB * NQ) / 64, 4), dim3(256), 0, stream,
                     ocat, WcThi, WcTlo, bc, mhf);
  hipLaunchKernelGGL(node_split, dim3(8000), dim3(256), 0, stream, nodes, nhi, nlo);
  hipLaunchKernelGGL(final_probs_mfma, dim3(NQ / 16, BB), dim3(256), 0, stream,
                     mhf, nhi, nlo, mask, flags, out);
}